// Round 6
// baseline (873.944 us; speedup 1.0000x reference)
//
#include <hip/hip_runtime.h>

#define K_CODES 4096
#define D 256
#define N_VEC 32768
#define N_ELEM 8388608   // 32*256*32*32
#define WINDOW 2e-4f
#define NSLOT 8
#define KSPLIT 4
#define KT_ITERS 8   // 1024 codes per block / 128
#define RB 8         // rescan batch

typedef _Float16 f16x8 __attribute__((ext_vector_type(8)));
typedef float f32x4 __attribute__((ext_vector_type(4)));
typedef const __attribute__((address_space(1))) _Float16* gptr_t;
typedef __attribute__((address_space(3))) _Float16* lptr_t;

// ws layout (bytes)
#define WS_LOSS 0
#define WS_COUNT 8
#define WS_IDX 256
#define WS_LIST (WS_IDX + N_VEC * 4)
#define WS_ESQ (WS_LIST + N_VEC * 4)
#define WS_ZSQ (WS_ESQ + K_CODES * 4)
#define WS_CAND (WS_ZSQ + N_VEC * 4)
#define WS_APACK (WS_CAND + NSLOT * N_VEC * 8)          // f16[N_VEC][512]
#define WS_BPACK (WS_APACK + (size_t)N_VEC * 512 * 2)   // f16[K_CODES][512]

__device__ __forceinline__ unsigned long long pack_key(float s, int idx) {
  const unsigned u = __float_as_uint(s);
  const unsigned mk = (u & 0x80000000u) ? ~u : (u | 0x80000000u);
  return ((unsigned long long)mk << 12) | (unsigned long long)(unsigned)idx;
}
__device__ __forceinline__ float key_score(unsigned long long k) {
  const unsigned mk = (unsigned)(k >> 12);
  const unsigned u = (mk & 0x80000000u) ? (mk & 0x7fffffffu) : ~mk;
  return __uint_as_float(u);
}

// ---- e_sq: fp32-squared terms, f64 accumulate, f32 round (frozen: R3) ------
__global__ __launch_bounds__(256) void esq_kernel(const float* __restrict__ cb,
                                                  float* __restrict__ esq) {
  const int lane = threadIdx.x & 63;
  const int k = blockIdx.x * 4 + (threadIdx.x >> 6);
  const float* row = cb + (size_t)k * D;
  double s = 0.;
#pragma unroll
  for (int j = 0; j < 4; ++j) {
    const float v = row[lane + 64 * j];
    s += (double)__fmul_rn(v, v);
  }
#pragma unroll
  for (int off = 32; off > 0; off >>= 1) s += __shfl_down(s, off, 64);
  if (lane == 0) esq[k] = (float)s;
}

// ---- z_sq per position (frozen: R3) ----------------------------------------
__global__ __launch_bounds__(256) void zsq_kernel(const float* __restrict__ z,
                                                  float* __restrict__ zsq) {
  const int n = blockIdx.x * 256 + threadIdx.x;
  const int b = n >> 10;
  const int hw = n & 1023;
  const float* p = z + ((size_t)b << 18) + hw;
  double a0 = 0., a1 = 0., a2 = 0., a3 = 0.;
  for (int c = 0; c < D; c += 4) {
    const float v0 = p[(size_t)(c + 0) << 10];
    const float v1 = p[(size_t)(c + 1) << 10];
    const float v2 = p[(size_t)(c + 2) << 10];
    const float v3 = p[(size_t)(c + 3) << 10];
    a0 += (double)__fmul_rn(v0, v0);
    a1 += (double)__fmul_rn(v1, v1);
    a2 += (double)__fmul_rn(v2, v2);
    a3 += (double)__fmul_rn(v3, v3);
  }
  zsq[n] = (float)((a0 + a1) + (a2 + a3));
}

// ---- pack z -> A_packed[n][512] f16: [z_hi | (z - z_hi)*2048] --------------
__global__ __launch_bounds__(256) void pack_z_kernel(const float* __restrict__ z,
                                                     _Float16* __restrict__ Ap) {
  __shared__ float zs[64][65];
  const int t = threadIdx.x;
  const int n0 = blockIdx.x * 64, c0 = blockIdx.y * 64;
  const int b = n0 >> 10, hw0 = n0 & 1023;
  const float* zb = z + ((size_t)b << 18) + hw0;
#pragma unroll
  for (int p = 0; p < 16; ++p) {
    const int cl = p * 4 + (t >> 6);
    zs[cl][t & 63] = zb[((size_t)(c0 + cl) << 10) + (t & 63)];
  }
  __syncthreads();
  const int nl = t >> 2, q = t & 3;
  f16x8 H0, H1, L0, L1;
#pragma unroll
  for (int j = 0; j < 8; ++j) {
    const float v = zs[q * 16 + j][nl];
    const _Float16 hh = (_Float16)v;
    H0[j] = hh;
    L0[j] = (_Float16)((v - (float)hh) * 2048.f);
    const float v2 = zs[q * 16 + 8 + j][nl];
    const _Float16 h2 = (_Float16)v2;
    H1[j] = h2;
    L1[j] = (_Float16)((v2 - (float)h2) * 2048.f);
  }
  _Float16* o = Ap + (size_t)(n0 + nl) * 512 + c0 + q * 16;
  *(f16x8*)o = H0;
  *((f16x8*)o + 1) = H1;
  *(f16x8*)(o + 256) = L0;
  *((f16x8*)(o + 256) + 1) = L1;
}

// ---- pack cb -> B_packed[k][512] f16: [256*e | (256*e)/2048] ---------------
__global__ __launch_bounds__(256) void pack_cb_kernel(const float* __restrict__ cb,
                                                      _Float16* __restrict__ Bp) {
  const int tg = blockIdx.x * 256 + threadIdx.x;  // 65536 total
  const int k = tg >> 4, q = tg & 15;
  const float* row = cb + (size_t)k * D + q * 16;
  f16x8 H0, H1, L0, L1;
#pragma unroll
  for (int j = 0; j < 8; ++j) {
    const _Float16 h0 = (_Float16)(row[j] * 256.f);
    H0[j] = h0;
    L0[j] = (_Float16)((float)h0 * (1.f / 2048.f));
    const _Float16 h1 = (_Float16)(row[8 + j] * 256.f);
    H1[j] = h1;
    L1[j] = (_Float16)((float)h1 * (1.f / 2048.f));
  }
  _Float16* o = Bp + (size_t)k * 512 + q * 16;
  *(f16x8*)o = H0;
  *((f16x8*)o + 1) = H1;
  *(f16x8*)(o + 256) = L0;
  *((f16x8*)(o + 256) + 1) = L1;
}

// ---- MFMA distance + top-2: 128n x 128codes tile, KSPLIT=4 -----------------
// fine score = esq[k] - acc/128, acc = 256*dot(z,e) via f16 split GEMM
__global__ __launch_bounds__(256, 4) void mfma_dist_kernel(
    const _Float16* __restrict__ Ap, const _Float16* __restrict__ Bp,
    const float* __restrict__ esq, unsigned long long* __restrict__ cand) {
  __shared__ _Float16 As[128 * 64];  // [n][kk] 128B rows, g-groups XOR-swizzled
  __shared__ _Float16 Bs[128 * 64];  // [code][kk] same
  __shared__ unsigned long long mbuf[128][2];
  const int tid = threadIdx.x;
  const int lane = tid & 63;
  const int w = tid >> 6;
  const int wn = w & 1, wk = w >> 1;
  const int n0 = blockIdx.x * 128;
  const int quad = lane >> 4;
  const int l16 = lane & 15;

  float s1[4], s2[4];
  int i1[4], i2[4];
#pragma unroll
  for (int i = 0; i < 4; ++i) {
    s1[i] = 3.4e38f; s2[i] = 3.4e38f; i1[i] = 0; i2[i] = 0;
  }

  for (int kt = 0; kt < KT_ITERS; ++kt) {
    const int k0 = blockIdx.y * 1024 + kt * 128;
    f32x4 acc[4][4];
#pragma unroll
    for (int ci = 0; ci < 4; ++ci)
#pragma unroll
      for (int nj = 0; nj < 4; ++nj) acc[ci][nj] = (f32x4)0.f;

    for (int c = 0; c < 8; ++c) {
      // stage: lane-contiguous LDS writes; global g-group XOR'd by row&7
#pragma unroll
      for (int i = 0; i < 4; ++i) {
        const int off = i * 256 + tid;
        const int row = off >> 3;
        const int g = (off & 7) ^ (row & 7);
        const _Float16* gpA = Ap + (size_t)(n0 + row) * 512 + c * 64 + g * 8;
        const _Float16* gpB = Bp + (size_t)(k0 + row) * 512 + c * 64 + g * 8;
        _Float16* lpA = As + (size_t)(i * 256 + w * 64) * 8;
        _Float16* lpB = Bs + (size_t)(i * 256 + w * 64) * 8;
        __builtin_amdgcn_global_load_lds((gptr_t)gpA, (lptr_t)lpA, 16, 0, 0);
        __builtin_amdgcn_global_load_lds((gptr_t)gpB, (lptr_t)lpB, 16, 0, 0);
      }
      __syncthreads();
#pragma unroll
      for (int ks = 0; ks < 2; ++ks) {
        f16x8 a[4], b[4];
#pragma unroll
        for (int ci = 0; ci < 4; ++ci) {
          const int row = wk * 64 + ci * 16 + l16;
          const int g = (ks * 4 + quad) ^ (row & 7);
          a[ci] = *(const f16x8*)(Bs + row * 64 + g * 8);
        }
#pragma unroll
        for (int nj = 0; nj < 4; ++nj) {
          const int row = wn * 64 + nj * 16 + l16;
          const int g = (ks * 4 + quad) ^ (row & 7);
          b[nj] = *(const f16x8*)(As + row * 64 + g * 8);
        }
#pragma unroll
        for (int ci = 0; ci < 4; ++ci)
#pragma unroll
          for (int nj = 0; nj < 4; ++nj)
            acc[ci][nj] = __builtin_amdgcn_mfma_f32_16x16x32_f16(
                a[ci], b[nj], acc[ci][nj], 0, 0, 0);
      }
      __syncthreads();
    }
    // fold 128 codes into running top-2 (codes ascend -> ties keep low idx)
#pragma unroll
    for (int ci = 0; ci < 4; ++ci) {
      const int row0 = wk * 64 + ci * 16 + quad * 4;
      const float4 e4 = *(const float4*)&esq[k0 + row0];
      const float ev[4] = {e4.x, e4.y, e4.z, e4.w};
#pragma unroll
      for (int r = 0; r < 4; ++r) {
        const int code = k0 + row0 + r;
#pragma unroll
        for (int nj = 0; nj < 4; ++nj) {
          const float s = fmaf(acc[ci][nj][r], -0.0078125f, ev[r]);
          if (s < s1[nj]) {
            s2[nj] = s1[nj]; i2[nj] = i1[nj]; s1[nj] = s; i1[nj] = code;
          } else if (s < s2[nj]) {
            s2[nj] = s; i2[nj] = code;
          }
        }
      }
    }
  }
  // cross-lane merge over the 4 row-quads (lanes l, l^16, l^32, l^48)
  unsigned long long k1[4], k2[4];
#pragma unroll
  for (int nj = 0; nj < 4; ++nj) {
    float a1 = s1[nj], a2 = s2[nj];
    int ai1 = i1[nj], ai2 = i2[nj];
#pragma unroll
    for (int m = 16; m <= 32; m <<= 1) {
      float b1 = __shfl_xor(a1, m, 64);
      int bi1 = __shfl_xor(ai1, m, 64);
      float b2 = __shfl_xor(a2, m, 64);
      int bi2 = __shfl_xor(ai2, m, 64);
      if (b1 < a1 || (b1 == a1 && bi1 < ai1)) {
        float t = a1; a1 = b1; b1 = t;
        int ti = ai1; ai1 = bi1; bi1 = ti;
        t = a2; a2 = b2; b2 = t;
        ti = ai2; ai2 = bi2; bi2 = ti;
      }
      if (b1 < a2 || (b1 == a2 && bi1 < ai2)) { a2 = b1; ai2 = bi1; }
    }
    k1[nj] = pack_key(a1, ai1);
    k2[nj] = pack_key(a2, ai2);
  }
  // cross-wk merge inside the block: wk=1 posts its pairs, wk=0 finalizes
  if (wk == 1 && quad == 0) {
#pragma unroll
    for (int nj = 0; nj < 4; ++nj) {
      const int nl = wn * 64 + nj * 16 + l16;
      mbuf[nl][0] = k1[nj];
      mbuf[nl][1] = k2[nj];
    }
  }
  __syncthreads();
  if (wk == 0 && quad == 0) {
#pragma unroll
    for (int nj = 0; nj < 4; ++nj) {
      const int nl = wn * 64 + nj * 16 + l16;
      const unsigned long long b1 = mbuf[nl][0];
      const unsigned long long b2 = mbuf[nl][1];
      const unsigned long long m1 = min(k1[nj], b1);
      const unsigned long long m2 = min(max(k1[nj], b1), min(k2[nj], b2));
      const size_t n = n0 + nl;
      cand[(size_t)(blockIdx.y * 2 + 0) * N_VEC + n] = m1;
      cand[(size_t)(blockIdx.y * 2 + 1) * N_VEC + n] = m2;
    }
  }
}

// ---- merge 8 candidate slots; flag near-window positions -------------------
__global__ __launch_bounds__(256) void merge_kernel(
    const unsigned long long* __restrict__ cand, int* __restrict__ idx,
    int* __restrict__ list, unsigned int* __restrict__ count) {
  const int n = blockIdx.x * 256 + threadIdx.x;
  unsigned long long m1 = ~0ull, m2 = ~0ull;
#pragma unroll
  for (int s = 0; s < NSLOT; ++s) {
    const unsigned long long c = cand[(size_t)s * N_VEC + n];
    if (c < m1) { m2 = m1; m1 = c; }
    else if (c < m2) { m2 = c; }
  }
  idx[n] = (int)(m1 & 0xFFFULL);
  if (key_score(m2) - key_score(m1) < WINDOW) {
    const unsigned pos = atomicAdd(count, 1u);
    if (pos < N_VEC) list[pos] = n;
  }
}

// ---- rescan flagged positions, batched x8: np fp32 chain emulation ---------
// d[k] = fl( fl(z_sq - fl(2 * (float)dot64)) + e_sq[k] ), argmin ties->low k
__global__ __launch_bounds__(256) void rescan_kernel(
    const float* __restrict__ z, const float* __restrict__ cb,
    const float* __restrict__ esq, const float* __restrict__ zsq,
    const int* __restrict__ list, const unsigned int* __restrict__ count,
    int* __restrict__ idx) {
  __shared__ float zrow[RB][D];   // 8 KB
  __shared__ int nlist[RB];
  __shared__ float dred4[4][RB];
  __shared__ int kred4[4][RB];
  const int tid = threadIdx.x;
  const int lane = tid & 63;
  const int w = tid >> 6;
  unsigned int cnt = *count;
  if (cnt > N_VEC) cnt = N_VEC;
  for (unsigned int base = blockIdx.x * RB; base < cnt;
       base += gridDim.x * RB) {
    const int nb = (int)min((unsigned)RB, cnt - base);
    if (tid < nb) nlist[tid] = list[base + tid];
    __syncthreads();
    // stage the nb z-rows (strided gather; small traffic)
    for (int e = tid; e < nb * D; e += 256) {
      const int p = e >> 8, c = e & 255;
      const int n = nlist[p];
      const int b = n >> 10, hw = n & 1023;
      zrow[p][c] = z[((size_t)b << 18) + ((size_t)c << 10) + hw];
    }
    __syncthreads();
    float zs_r[RB];
#pragma unroll
    for (int p = 0; p < RB; ++p)
      zs_r[p] = (p < nb) ? zsq[nlist[p]] : 0.f;

    float bestd[RB];
    int bestk[RB];
#pragma unroll
    for (int p = 0; p < RB; ++p) { bestd[p] = 3.4e38f; bestk[p] = 0; }

    for (int k = tid; k < K_CODES; k += 256) {
      const float* row = cb + (size_t)k * D;
      double acc[RB];
#pragma unroll
      for (int p = 0; p < RB; ++p) acc[p] = 0.;
      for (int c = 0; c < D; c += 4) {
        const float4 r4 = *(const float4*)(row + c);
#pragma unroll
        for (int p = 0; p < RB; ++p) {
          const float4 z4 = *(const float4*)&zrow[p][c];
          acc[p] = fma((double)z4.x, (double)r4.x, acc[p]);
          acc[p] = fma((double)z4.y, (double)r4.y, acc[p]);
          acc[p] = fma((double)z4.z, (double)r4.z, acc[p]);
          acc[p] = fma((double)z4.w, (double)r4.w, acc[p]);
        }
      }
      const float ek = esq[k];
      for (int p = 0; p < nb; ++p) {
        const float dotf = (float)acc[p];
        const float tmp = __fsub_rn(zs_r[p], __fmul_rn(2.0f, dotf));
        const float d = __fadd_rn(tmp, ek);
        if (d < bestd[p]) { bestd[p] = d; bestk[p] = k; }
      }
    }
    // wave-level reduce (k-subsets disjoint per lane), then cross-wave in LDS
    for (int p = 0; p < nb; ++p) {
      float d = bestd[p];
      int kk = bestk[p];
#pragma unroll
      for (int off = 32; off > 0; off >>= 1) {
        const float od = __shfl_down(d, off, 64);
        const int ok = __shfl_down(kk, off, 64);
        if (od < d || (od == d && ok < kk)) { d = od; kk = ok; }
      }
      if (lane == 0) { dred4[w][p] = d; kred4[w][p] = kk; }
    }
    __syncthreads();
    if (tid < nb) {
      float d = dred4[0][tid];
      int kk = kred4[0][tid];
#pragma unroll
      for (int ww = 1; ww < 4; ++ww) {
        const float od = dred4[ww][tid];
        const int ok = kred4[ww][tid];
        if (od < d || (od == d && ok < kk)) { d = od; kk = ok; }
      }
      idx[nlist[tid]] = kk;
    }
    __syncthreads();
  }
}

// ---- gather z_q, write z_q_st + indices, accumulate loss (frozen: R3) ------
__global__ __launch_bounds__(256) void gather_kernel(
    const float* __restrict__ z, const float* __restrict__ cb,
    const int* __restrict__ idxarr, float* __restrict__ out,
    float* __restrict__ loss_acc) {
  const int tid = threadIdx.x;
  const int n0 = blockIdx.x * 64;
  const int hwl = tid & 63;
  const int c0 = tid >> 6;
  const int n = n0 + hwl;
  const int b = n >> 10;
  const int hw = n & 1023;
  const int idx = idxarr[n];
  if (tid < 64) out[(size_t)N_ELEM + 1 + n] = (float)idx;
  const float* crow = cb + (size_t)idx * D;
  const size_t obase = ((size_t)b << 18) + hw;
  float part = 0.f;
#pragma unroll
  for (int c = c0; c < D; c += 4) {
    const float v = crow[c];
    const size_t o = obase + ((size_t)c << 10);
    const float diff = v - z[o];
    out[o] = v;
    part = fmaf(diff, diff, part);
  }
#pragma unroll
  for (int off = 32; off > 0; off >>= 1) part += __shfl_down(part, off, 64);
  __shared__ float red[4];
  if ((tid & 63) == 0) red[tid >> 6] = part;
  __syncthreads();
  if (tid == 0) atomicAdd(loss_acc, red[0] + red[1] + red[2] + red[3]);
}

__global__ void finalize_kernel(const float* __restrict__ loss_acc,
                                float* __restrict__ out) {
  if (threadIdx.x == 0 && blockIdx.x == 0)
    out[N_ELEM] = 1.25f * loss_acc[0] * (1.0f / (float)N_ELEM);
}

extern "C" void kernel_launch(void* const* d_in, const int* in_sizes, int n_in,
                              void* d_out, int out_size, void* d_ws,
                              size_t ws_size, hipStream_t stream) {
  const float* z = (const float*)d_in[0];
  const float* cb = (const float*)d_in[1];
  float* out = (float*)d_out;
  char* ws = (char*)d_ws;
  float* loss_acc = (float*)(ws + WS_LOSS);
  unsigned int* count = (unsigned int*)(ws + WS_COUNT);
  int* idx = (int*)(ws + WS_IDX);
  int* list = (int*)(ws + WS_LIST);
  float* esq = (float*)(ws + WS_ESQ);
  float* zsq = (float*)(ws + WS_ZSQ);
  unsigned long long* cand = (unsigned long long*)(ws + WS_CAND);
  _Float16* Ap = (_Float16*)(ws + WS_APACK);
  _Float16* Bp = (_Float16*)(ws + WS_BPACK);

  hipMemsetAsync(ws, 0, 256, stream);
  esq_kernel<<<K_CODES / 4, 256, 0, stream>>>(cb, esq);
  zsq_kernel<<<N_VEC / 256, 256, 0, stream>>>(z, zsq);
  pack_z_kernel<<<dim3(N_VEC / 64, 4), 256, 0, stream>>>(z, Ap);
  pack_cb_kernel<<<256, 256, 0, stream>>>(cb, Bp);
  mfma_dist_kernel<<<dim3(N_VEC / 128, KSPLIT), 256, 0, stream>>>(Ap, Bp, esq,
                                                                  cand);
  merge_kernel<<<N_VEC / 256, 256, 0, stream>>>(cand, idx, list, count);
  rescan_kernel<<<256, 256, 0, stream>>>(z, cb, esq, zsq, list, count, idx);
  gather_kernel<<<N_VEC / 64, 256, 0, stream>>>(z, cb, idx, out, loss_acc);
  finalize_kernel<<<1, 64, 0, stream>>>(loss_acc, out);
}

// Round 7
// 462.693 us; speedup vs baseline: 1.8888x; 1.8888x over previous
//
#include <hip/hip_runtime.h>

#define K_CODES 4096
#define D 256
#define N_VEC 32768
#define N_ELEM 8388608   // 32*256*32*32
#define WINDOW 2e-4f
#define NSLOT 8
#define KSPLIT 4
#define KT_ITERS 8   // 1024 codes per block / 128

typedef _Float16 f16x8 __attribute__((ext_vector_type(8)));
typedef float f32x4 __attribute__((ext_vector_type(4)));
typedef const __attribute__((address_space(1))) _Float16* gptr_t;
typedef __attribute__((address_space(3))) _Float16* lptr_t;

// ws layout (bytes)
#define WS_LOSS 0
#define WS_COUNT 8
#define WS_IDX 256
#define WS_LIST (WS_IDX + N_VEC * 4)
#define WS_ESQ (WS_LIST + N_VEC * 4)
#define WS_ZSQ (WS_ESQ + K_CODES * 4)
#define WS_CAND (WS_ZSQ + N_VEC * 4)
#define WS_APACK (WS_CAND + NSLOT * N_VEC * 8)          // f16[N_VEC][512]
#define WS_BPACK (WS_APACK + (size_t)N_VEC * 512 * 2)   // f16[K_CODES][512]
#define WS_RFIN (WS_BPACK + (size_t)K_CODES * 512 * 2)  // ull[N_VEC]

__device__ __forceinline__ unsigned long long pack_key(float s, int idx) {
  const unsigned u = __float_as_uint(s);
  const unsigned mk = (u & 0x80000000u) ? ~u : (u | 0x80000000u);
  return ((unsigned long long)mk << 12) | (unsigned long long)(unsigned)idx;
}
__device__ __forceinline__ float key_score(unsigned long long k) {
  const unsigned mk = (unsigned)(k >> 12);
  const unsigned u = (mk & 0x80000000u) ? (mk & 0x7fffffffu) : ~mk;
  return __uint_as_float(u);
}

// ---- e_sq: fp32-squared terms, f64 accumulate, f32 round (frozen: R3) ------
__global__ __launch_bounds__(256) void esq_kernel(const float* __restrict__ cb,
                                                  float* __restrict__ esq) {
  const int lane = threadIdx.x & 63;
  const int k = blockIdx.x * 4 + (threadIdx.x >> 6);
  const float* row = cb + (size_t)k * D;
  double s = 0.;
#pragma unroll
  for (int j = 0; j < 4; ++j) {
    const float v = row[lane + 64 * j];
    s += (double)__fmul_rn(v, v);
  }
#pragma unroll
  for (int off = 32; off > 0; off >>= 1) s += __shfl_down(s, off, 64);
  if (lane == 0) esq[k] = (float)s;
}

// ---- z_sq per position (frozen: R3) ----------------------------------------
__global__ __launch_bounds__(256) void zsq_kernel(const float* __restrict__ z,
                                                  float* __restrict__ zsq) {
  const int n = blockIdx.x * 256 + threadIdx.x;
  const int b = n >> 10;
  const int hw = n & 1023;
  const float* p = z + ((size_t)b << 18) + hw;
  double a0 = 0., a1 = 0., a2 = 0., a3 = 0.;
  for (int c = 0; c < D; c += 4) {
    const float v0 = p[(size_t)(c + 0) << 10];
    const float v1 = p[(size_t)(c + 1) << 10];
    const float v2 = p[(size_t)(c + 2) << 10];
    const float v3 = p[(size_t)(c + 3) << 10];
    a0 += (double)__fmul_rn(v0, v0);
    a1 += (double)__fmul_rn(v1, v1);
    a2 += (double)__fmul_rn(v2, v2);
    a3 += (double)__fmul_rn(v3, v3);
  }
  zsq[n] = (float)((a0 + a1) + (a2 + a3));
}

// ---- pack z -> A_packed[n][512] f16: [z_hi | (z - z_hi)*2048] --------------
__global__ __launch_bounds__(256) void pack_z_kernel(const float* __restrict__ z,
                                                     _Float16* __restrict__ Ap) {
  __shared__ float zs[64][65];
  const int t = threadIdx.x;
  const int n0 = blockIdx.x * 64, c0 = blockIdx.y * 64;
  const int b = n0 >> 10, hw0 = n0 & 1023;
  const float* zb = z + ((size_t)b << 18) + hw0;
#pragma unroll
  for (int p = 0; p < 16; ++p) {
    const int cl = p * 4 + (t >> 6);
    zs[cl][t & 63] = zb[((size_t)(c0 + cl) << 10) + (t & 63)];
  }
  __syncthreads();
  const int nl = t >> 2, q = t & 3;
  f16x8 H0, H1, L0, L1;
#pragma unroll
  for (int j = 0; j < 8; ++j) {
    const float v = zs[q * 16 + j][nl];
    const _Float16 hh = (_Float16)v;
    H0[j] = hh;
    L0[j] = (_Float16)((v - (float)hh) * 2048.f);
    const float v2 = zs[q * 16 + 8 + j][nl];
    const _Float16 h2 = (_Float16)v2;
    H1[j] = h2;
    L1[j] = (_Float16)((v2 - (float)h2) * 2048.f);
  }
  _Float16* o = Ap + (size_t)(n0 + nl) * 512 + c0 + q * 16;
  *(f16x8*)o = H0;
  *((f16x8*)o + 1) = H1;
  *(f16x8*)(o + 256) = L0;
  *((f16x8*)(o + 256) + 1) = L1;
}

// ---- pack cb -> B_packed[k][512] f16: [256*e | (256*e)/2048] ---------------
__global__ __launch_bounds__(256) void pack_cb_kernel(const float* __restrict__ cb,
                                                      _Float16* __restrict__ Bp) {
  const int tg = blockIdx.x * 256 + threadIdx.x;  // 65536 total
  const int k = tg >> 4, q = tg & 15;
  const float* row = cb + (size_t)k * D + q * 16;
  f16x8 H0, H1, L0, L1;
#pragma unroll
  for (int j = 0; j < 8; ++j) {
    const _Float16 h0 = (_Float16)(row[j] * 256.f);
    H0[j] = h0;
    L0[j] = (_Float16)((float)h0 * (1.f / 2048.f));
    const _Float16 h1 = (_Float16)(row[8 + j] * 256.f);
    H1[j] = h1;
    L1[j] = (_Float16)((float)h1 * (1.f / 2048.f));
  }
  _Float16* o = Bp + (size_t)k * 512 + q * 16;
  *(f16x8*)o = H0;
  *((f16x8*)o + 1) = H1;
  *(f16x8*)(o + 256) = L0;
  *((f16x8*)(o + 256) + 1) = L1;
}

// ---- MFMA distance + top-2: 128n x 128codes tile, KSPLIT=4 -----------------
// fine score = esq[k] - acc/128, acc = 256*dot(z,e) via f16 split GEMM
__global__ __launch_bounds__(256, 4) void mfma_dist_kernel(
    const _Float16* __restrict__ Ap, const _Float16* __restrict__ Bp,
    const float* __restrict__ esq, unsigned long long* __restrict__ cand) {
  __shared__ _Float16 As[128 * 64];  // [n][kk] 128B rows, g-groups XOR-swizzled
  __shared__ _Float16 Bs[128 * 64];  // [code][kk] same
  __shared__ unsigned long long mbuf[128][2];
  const int tid = threadIdx.x;
  const int lane = tid & 63;
  const int w = tid >> 6;
  const int wn = w & 1, wk = w >> 1;
  const int n0 = blockIdx.x * 128;
  const int quad = lane >> 4;
  const int l16 = lane & 15;

  float s1[4], s2[4];
  int i1[4], i2[4];
#pragma unroll
  for (int i = 0; i < 4; ++i) {
    s1[i] = 3.4e38f; s2[i] = 3.4e38f; i1[i] = 0; i2[i] = 0;
  }

  for (int kt = 0; kt < KT_ITERS; ++kt) {
    const int k0 = blockIdx.y * 1024 + kt * 128;
    f32x4 acc[4][4];
#pragma unroll
    for (int ci = 0; ci < 4; ++ci)
#pragma unroll
      for (int nj = 0; nj < 4; ++nj) acc[ci][nj] = (f32x4)0.f;

    for (int c = 0; c < 8; ++c) {
      // stage: lane-contiguous LDS writes; global g-group XOR'd by row&7
#pragma unroll
      for (int i = 0; i < 4; ++i) {
        const int off = i * 256 + tid;
        const int row = off >> 3;
        const int g = (off & 7) ^ (row & 7);
        const _Float16* gpA = Ap + (size_t)(n0 + row) * 512 + c * 64 + g * 8;
        const _Float16* gpB = Bp + (size_t)(k0 + row) * 512 + c * 64 + g * 8;
        _Float16* lpA = As + (size_t)(i * 256 + w * 64) * 8;
        _Float16* lpB = Bs + (size_t)(i * 256 + w * 64) * 8;
        __builtin_amdgcn_global_load_lds((gptr_t)gpA, (lptr_t)lpA, 16, 0, 0);
        __builtin_amdgcn_global_load_lds((gptr_t)gpB, (lptr_t)lpB, 16, 0, 0);
      }
      __syncthreads();
#pragma unroll
      for (int ks = 0; ks < 2; ++ks) {
        f16x8 a[4], b[4];
#pragma unroll
        for (int ci = 0; ci < 4; ++ci) {
          const int row = wk * 64 + ci * 16 + l16;
          const int g = (ks * 4 + quad) ^ (row & 7);
          a[ci] = *(const f16x8*)(Bs + row * 64 + g * 8);
        }
#pragma unroll
        for (int nj = 0; nj < 4; ++nj) {
          const int row = wn * 64 + nj * 16 + l16;
          const int g = (ks * 4 + quad) ^ (row & 7);
          b[nj] = *(const f16x8*)(As + row * 64 + g * 8);
        }
#pragma unroll
        for (int ci = 0; ci < 4; ++ci)
#pragma unroll
          for (int nj = 0; nj < 4; ++nj)
            acc[ci][nj] = __builtin_amdgcn_mfma_f32_16x16x32_f16(
                a[ci], b[nj], acc[ci][nj], 0, 0, 0);
      }
      __syncthreads();
    }
    // fold 128 codes into running top-2 (codes ascend -> ties keep low idx)
#pragma unroll
    for (int ci = 0; ci < 4; ++ci) {
      const int row0 = wk * 64 + ci * 16 + quad * 4;
      const float4 e4 = *(const float4*)&esq[k0 + row0];
      const float ev[4] = {e4.x, e4.y, e4.z, e4.w};
#pragma unroll
      for (int r = 0; r < 4; ++r) {
        const int code = k0 + row0 + r;
#pragma unroll
        for (int nj = 0; nj < 4; ++nj) {
          const float s = fmaf(acc[ci][nj][r], -0.0078125f, ev[r]);
          if (s < s1[nj]) {
            s2[nj] = s1[nj]; i2[nj] = i1[nj]; s1[nj] = s; i1[nj] = code;
          } else if (s < s2[nj]) {
            s2[nj] = s; i2[nj] = code;
          }
        }
      }
    }
  }
  // cross-lane merge over the 4 row-quads (lanes l, l^16, l^32, l^48)
  unsigned long long k1[4], k2[4];
#pragma unroll
  for (int nj = 0; nj < 4; ++nj) {
    float a1 = s1[nj], a2 = s2[nj];
    int ai1 = i1[nj], ai2 = i2[nj];
#pragma unroll
    for (int m = 16; m <= 32; m <<= 1) {
      float b1 = __shfl_xor(a1, m, 64);
      int bi1 = __shfl_xor(ai1, m, 64);
      float b2 = __shfl_xor(a2, m, 64);
      int bi2 = __shfl_xor(ai2, m, 64);
      if (b1 < a1 || (b1 == a1 && bi1 < ai1)) {
        float t = a1; a1 = b1; b1 = t;
        int ti = ai1; ai1 = bi1; bi1 = ti;
        t = a2; a2 = b2; b2 = t;
        ti = ai2; ai2 = bi2; bi2 = ti;
      }
      if (b1 < a2 || (b1 == a2 && bi1 < ai2)) { a2 = b1; ai2 = bi1; }
    }
    k1[nj] = pack_key(a1, ai1);
    k2[nj] = pack_key(a2, ai2);
  }
  // cross-wk merge inside the block: wk=1 posts its pairs, wk=0 finalizes
  if (wk == 1 && quad == 0) {
#pragma unroll
    for (int nj = 0; nj < 4; ++nj) {
      const int nl = wn * 64 + nj * 16 + l16;
      mbuf[nl][0] = k1[nj];
      mbuf[nl][1] = k2[nj];
    }
  }
  __syncthreads();
  if (wk == 0 && quad == 0) {
#pragma unroll
    for (int nj = 0; nj < 4; ++nj) {
      const int nl = wn * 64 + nj * 16 + l16;
      const unsigned long long b1 = mbuf[nl][0];
      const unsigned long long b2 = mbuf[nl][1];
      const unsigned long long m1 = min(k1[nj], b1);
      const unsigned long long m2 = min(max(k1[nj], b1), min(k2[nj], b2));
      const size_t n = n0 + nl;
      cand[(size_t)(blockIdx.y * 2 + 0) * N_VEC + n] = m1;
      cand[(size_t)(blockIdx.y * 2 + 1) * N_VEC + n] = m2;
    }
  }
}

// ---- merge 8 candidate slots; flag near-window positions -------------------
__global__ __launch_bounds__(256) void merge_kernel(
    const unsigned long long* __restrict__ cand, int* __restrict__ idx,
    int* __restrict__ list, unsigned int* __restrict__ count,
    unsigned long long* __restrict__ rfin) {
  const int n = blockIdx.x * 256 + threadIdx.x;
  unsigned long long m1 = ~0ull, m2 = ~0ull;
#pragma unroll
  for (int s = 0; s < NSLOT; ++s) {
    const unsigned long long c = cand[(size_t)s * N_VEC + n];
    if (c < m1) { m2 = m1; m1 = c; }
    else if (c < m2) { m2 = c; }
  }
  idx[n] = (int)(m1 & 0xFFFULL);
  if (key_score(m2) - key_score(m1) < WINDOW) {
    rfin[n] = ~0ull;
    const unsigned pos = atomicAdd(count, 1u);
    if (pos < N_VEC) list[pos] = n;
  }
}

// ---- rescan: work item = (position-pair, k-slice of 1024) ------------------
// frozen chain: d[k] = fl( fl(z_sq - fl(2*(float)dot64)) + e_sq[k] );
// winner via atomicMin on packed key (ties -> lowest k)
__global__ __launch_bounds__(256) void rescan_kernel(
    const float* __restrict__ z, const float* __restrict__ cb,
    const float* __restrict__ esq, const float* __restrict__ zsq,
    const int* __restrict__ list, const unsigned int* __restrict__ count,
    unsigned long long* __restrict__ rfin) {
  __shared__ float zrow[2][D];
  __shared__ int nloc[2];
  const int tid = threadIdx.x;
  const int lane = tid & 63;
  unsigned int cnt = *count;
  if (cnt > N_VEC) cnt = N_VEC;
  const unsigned nitems = ((cnt + 1) >> 1) * 4;
  for (unsigned item = blockIdx.x; item < nitems; item += gridDim.x) {
    const unsigned pair = item >> 2;
    const int slice = item & 3;
    __syncthreads();  // protect zrow/nloc reuse across grid-stride iters
    if (tid < 2) {
      const unsigned r = pair * 2 + tid;
      nloc[tid] = (r < cnt) ? list[r] : -1;
    }
    __syncthreads();
#pragma unroll
    for (int p = 0; p < 2; ++p) {
      const int n = nloc[p];
      if (n >= 0) {
        const int b = n >> 10, hw = n & 1023;
        zrow[p][tid] = z[((size_t)b << 18) + ((size_t)tid << 10) + hw];
      }
    }
    __syncthreads();
    const int n0 = nloc[0], n1 = nloc[1];
    const float zs0 = (n0 >= 0) ? zsq[n0] : 0.f;
    const float zs1 = (n1 >= 0) ? zsq[n1] : 0.f;
    unsigned long long best0 = ~0ull, best1 = ~0ull;
#pragma unroll
    for (int rr = 0; rr < 4; ++rr) {
      const int k = slice * 1024 + rr * 256 + tid;
      const float* row = cb + (size_t)k * D;
      double a0 = 0., a1 = 0., a2 = 0., a3 = 0.;
      double b0 = 0., b1 = 0., b2 = 0., b3 = 0.;
      for (int c = 0; c < D; c += 4) {
        const float4 r4 = *(const float4*)(row + c);
        const float4 z0 = *(const float4*)&zrow[0][c];
        const float4 z1 = *(const float4*)&zrow[1][c];
        a0 = fma((double)z0.x, (double)r4.x, a0);
        a1 = fma((double)z0.y, (double)r4.y, a1);
        a2 = fma((double)z0.z, (double)r4.z, a2);
        a3 = fma((double)z0.w, (double)r4.w, a3);
        b0 = fma((double)z1.x, (double)r4.x, b0);
        b1 = fma((double)z1.y, (double)r4.y, b1);
        b2 = fma((double)z1.z, (double)r4.z, b2);
        b3 = fma((double)z1.w, (double)r4.w, b3);
      }
      const float ek = esq[k];
      const float dot0 = (float)((a0 + a1) + (a2 + a3));
      const float d0 = __fadd_rn(__fsub_rn(zs0, __fmul_rn(2.0f, dot0)), ek);
      best0 = min(best0, pack_key(d0, k));
      const float dot1 = (float)((b0 + b1) + (b2 + b3));
      const float d1 = __fadd_rn(__fsub_rn(zs1, __fmul_rn(2.0f, dot1)), ek);
      best1 = min(best1, pack_key(d1, k));
    }
#pragma unroll
    for (int off = 32; off > 0; off >>= 1) {
      best0 = min(best0, __shfl_down(best0, off, 64));
      best1 = min(best1, __shfl_down(best1, off, 64));
    }
    if (lane == 0) {
      if (n0 >= 0) atomicMin(rfin + n0, best0);
      if (n1 >= 0) atomicMin(rfin + n1, best1);
    }
  }
}

// ---- writeback rescan winners into idx -------------------------------------
__global__ __launch_bounds__(256) void rescan_fin_kernel(
    const int* __restrict__ list, const unsigned int* __restrict__ count,
    const unsigned long long* __restrict__ rfin, int* __restrict__ idx) {
  unsigned int cnt = *count;
  if (cnt > N_VEC) cnt = N_VEC;
  const unsigned t = blockIdx.x * 256 + threadIdx.x;
  if (t < cnt) {
    const int n = list[t];
    idx[n] = (int)(rfin[n] & 0xFFFULL);
  }
}

// ---- gather z_q, write z_q_st + indices, accumulate loss (frozen: R3) ------
__global__ __launch_bounds__(256) void gather_kernel(
    const float* __restrict__ z, const float* __restrict__ cb,
    const int* __restrict__ idxarr, float* __restrict__ out,
    float* __restrict__ loss_acc) {
  const int tid = threadIdx.x;
  const int n0 = blockIdx.x * 64;
  const int hwl = tid & 63;
  const int c0 = tid >> 6;
  const int n = n0 + hwl;
  const int b = n >> 10;
  const int hw = n & 1023;
  const int idx = idxarr[n];
  if (tid < 64) out[(size_t)N_ELEM + 1 + n] = (float)idx;
  const float* crow = cb + (size_t)idx * D;
  const size_t obase = ((size_t)b << 18) + hw;
  float part = 0.f;
#pragma unroll
  for (int c = c0; c < D; c += 4) {
    const float v = crow[c];
    const size_t o = obase + ((size_t)c << 10);
    const float diff = v - z[o];
    out[o] = v;
    part = fmaf(diff, diff, part);
  }
#pragma unroll
  for (int off = 32; off > 0; off >>= 1) part += __shfl_down(part, off, 64);
  __shared__ float red[4];
  if ((tid & 63) == 0) red[tid >> 6] = part;
  __syncthreads();
  if (tid == 0) atomicAdd(loss_acc, red[0] + red[1] + red[2] + red[3]);
}

__global__ void finalize_kernel(const float* __restrict__ loss_acc,
                                float* __restrict__ out) {
  if (threadIdx.x == 0 && blockIdx.x == 0)
    out[N_ELEM] = 1.25f * loss_acc[0] * (1.0f / (float)N_ELEM);
}

extern "C" void kernel_launch(void* const* d_in, const int* in_sizes, int n_in,
                              void* d_out, int out_size, void* d_ws,
                              size_t ws_size, hipStream_t stream) {
  const float* z = (const float*)d_in[0];
  const float* cb = (const float*)d_in[1];
  float* out = (float*)d_out;
  char* ws = (char*)d_ws;
  float* loss_acc = (float*)(ws + WS_LOSS);
  unsigned int* count = (unsigned int*)(ws + WS_COUNT);
  int* idx = (int*)(ws + WS_IDX);
  int* list = (int*)(ws + WS_LIST);
  float* esq = (float*)(ws + WS_ESQ);
  float* zsq = (float*)(ws + WS_ZSQ);
  unsigned long long* cand = (unsigned long long*)(ws + WS_CAND);
  _Float16* Ap = (_Float16*)(ws + WS_APACK);
  _Float16* Bp = (_Float16*)(ws + WS_BPACK);
  unsigned long long* rfin = (unsigned long long*)(ws + WS_RFIN);

  hipMemsetAsync(ws, 0, 256, stream);
  esq_kernel<<<K_CODES / 4, 256, 0, stream>>>(cb, esq);
  zsq_kernel<<<N_VEC / 256, 256, 0, stream>>>(z, zsq);
  pack_z_kernel<<<dim3(N_VEC / 64, 4), 256, 0, stream>>>(z, Ap);
  pack_cb_kernel<<<256, 256, 0, stream>>>(cb, Bp);
  mfma_dist_kernel<<<dim3(N_VEC / 128, KSPLIT), 256, 0, stream>>>(Ap, Bp, esq,
                                                                  cand);
  merge_kernel<<<N_VEC / 256, 256, 0, stream>>>(cand, idx, list, count, rfin);
  rescan_kernel<<<2048, 256, 0, stream>>>(z, cb, esq, zsq, list, count, rfin);
  rescan_fin_kernel<<<N_VEC / 256, 256, 0, stream>>>(list, count, rfin, idx);
  gather_kernel<<<N_VEC / 64, 256, 0, stream>>>(z, cb, idx, out, loss_acc);
  finalize_kernel<<<1, 64, 0, stream>>>(loss_acc, out);
}

// Round 8
// 425.820 us; speedup vs baseline: 2.0524x; 1.0866x over previous
//
#include <hip/hip_runtime.h>

#define K_CODES 4096
#define D 256
#define N_VEC 32768
#define N_ELEM 8388608   // 32*256*32*32
#define WINDOW 3.5e-4f
#define NSLOT 8
#define KSPLIT 4
#define KT_ITERS 8   // 1024 codes per block / 128

typedef _Float16 f16x8 __attribute__((ext_vector_type(8)));
typedef float f32x4 __attribute__((ext_vector_type(4)));
typedef const __attribute__((address_space(1))) _Float16* gptr_t;
typedef __attribute__((address_space(3))) _Float16* lptr_t;

// ws layout (bytes)
#define WS_LOSS 0
#define WS_COUNT 8
#define WS_DONE 16
#define WS_IDX 256
#define WS_LIST (WS_IDX + N_VEC * 4)
#define WS_ESQ (WS_LIST + N_VEC * 4)
#define WS_ZSQ (WS_ESQ + K_CODES * 4)
#define WS_CAND (WS_ZSQ + N_VEC * 4)
#define WS_APACK (WS_CAND + NSLOT * N_VEC * 8)          // f16[N_VEC][256]
#define WS_BPACK (WS_APACK + (size_t)N_VEC * 256 * 2)   // f16[K_CODES][256]
#define WS_RFIN (WS_BPACK + (size_t)K_CODES * 256 * 2)  // ull[N_VEC]

// prep fusion block regions
#define PREP_PZ 2048   // pack_z: 512 n-tiles x 4 c-tiles
#define PREP_PCB 256
#define PREP_ESQ 1024
#define PREP_ZSQ 128
#define PREP_BLOCKS (PREP_PZ + PREP_PCB + PREP_ESQ + PREP_ZSQ)

__device__ __forceinline__ unsigned long long pack_key(float s, int idx) {
  const unsigned u = __float_as_uint(s);
  const unsigned mk = (u & 0x80000000u) ? ~u : (u | 0x80000000u);
  return ((unsigned long long)mk << 12) | (unsigned long long)(unsigned)idx;
}
__device__ __forceinline__ float key_score(unsigned long long k) {
  const unsigned mk = (unsigned)(k >> 12);
  const unsigned u = (mk & 0x80000000u) ? (mk & 0x7fffffffu) : ~mk;
  return __uint_as_float(u);
}

// ---- e_sq body: fp32-squared terms, f64 accumulate, f32 round (frozen) -----
__device__ void esq_body(int bx, const float* __restrict__ cb,
                         float* __restrict__ esq) {
  const int lane = threadIdx.x & 63;
  const int k = bx * 4 + (threadIdx.x >> 6);
  const float* row = cb + (size_t)k * D;
  double s = 0.;
#pragma unroll
  for (int j = 0; j < 4; ++j) {
    const float v = row[lane + 64 * j];
    s += (double)__fmul_rn(v, v);
  }
#pragma unroll
  for (int off = 32; off > 0; off >>= 1) s += __shfl_down(s, off, 64);
  if (lane == 0) esq[k] = (float)s;
}

// ---- z_sq body (frozen: R3 — deterministic per-position order) -------------
__device__ void zsq_body(int bx, const float* __restrict__ z,
                         float* __restrict__ zsq) {
  const int n = bx * 256 + threadIdx.x;
  const int b = n >> 10;
  const int hw = n & 1023;
  const float* p = z + ((size_t)b << 18) + hw;
  double a0 = 0., a1 = 0., a2 = 0., a3 = 0.;
  for (int c = 0; c < D; c += 4) {
    const float v0 = p[(size_t)(c + 0) << 10];
    const float v1 = p[(size_t)(c + 1) << 10];
    const float v2 = p[(size_t)(c + 2) << 10];
    const float v3 = p[(size_t)(c + 3) << 10];
    a0 += (double)__fmul_rn(v0, v0);
    a1 += (double)__fmul_rn(v1, v1);
    a2 += (double)__fmul_rn(v2, v2);
    a3 += (double)__fmul_rn(v3, v3);
  }
  zsq[n] = (float)((a0 + a1) + (a2 + a3));
}

// ---- pack z -> Ap[n][256] f16(z) (single-f16, no lo-term) ------------------
__device__ void pack_z_body(int bx, int by, const float* __restrict__ z,
                            _Float16* __restrict__ Ap) {
  __shared__ float zs[64][65];
  const int t = threadIdx.x;
  const int n0 = bx * 64, c0 = by * 64;
  const int b = n0 >> 10, hw0 = n0 & 1023;
  const float* zb = z + ((size_t)b << 18) + hw0;
#pragma unroll
  for (int p = 0; p < 16; ++p) {
    const int cl = p * 4 + (t >> 6);
    zs[cl][t & 63] = zb[((size_t)(c0 + cl) << 10) + (t & 63)];
  }
  __syncthreads();
  const int nl = t >> 2, q = t & 3;
  f16x8 H0, H1;
#pragma unroll
  for (int j = 0; j < 8; ++j) {
    H0[j] = (_Float16)zs[q * 16 + j][nl];
    H1[j] = (_Float16)zs[q * 16 + 8 + j][nl];
  }
  _Float16* o = Ap + (size_t)(n0 + nl) * 256 + c0 + q * 16;
  *(f16x8*)o = H0;
  *((f16x8*)o + 1) = H1;
}

// ---- pack cb -> Bp[k][256] f16(256*e) --------------------------------------
__device__ void pack_cb_body(int bx, const float* __restrict__ cb,
                             _Float16* __restrict__ Bp) {
  const int tg = bx * 256 + threadIdx.x;  // 65536 total
  const int k = tg >> 4, q = tg & 15;
  const float* row = cb + (size_t)k * D + q * 16;
  f16x8 H0, H1;
#pragma unroll
  for (int j = 0; j < 8; ++j) {
    H0[j] = (_Float16)(row[j] * 256.f);
    H1[j] = (_Float16)(row[8 + j] * 256.f);
  }
  _Float16* o = Bp + (size_t)k * 256 + q * 16;
  *(f16x8*)o = H0;
  *((f16x8*)o + 1) = H1;
}

// ---- fused prep: one launch for esq + zsq + pack_z + pack_cb ---------------
__global__ __launch_bounds__(256) void prep_kernel(const float* __restrict__ z,
                                                   const float* __restrict__ cb,
                                                   float* __restrict__ esq,
                                                   float* __restrict__ zsq,
                                                   _Float16* __restrict__ Ap,
                                                   _Float16* __restrict__ Bp) {
  const int b = blockIdx.x;
  if (b < PREP_PZ) {
    pack_z_body(b & 511, b >> 9, z, Ap);
  } else if (b < PREP_PZ + PREP_PCB) {
    pack_cb_body(b - PREP_PZ, cb, Bp);
  } else if (b < PREP_PZ + PREP_PCB + PREP_ESQ) {
    esq_body(b - PREP_PZ - PREP_PCB, cb, esq);
  } else {
    zsq_body(b - PREP_PZ - PREP_PCB - PREP_ESQ, z, zsq);
  }
}

// ---- MFMA distance + top-2: 128n x 128codes tile, K=256, KSPLIT=4 ----------
// fine score = esq[k] - acc/128, acc = dot(f16(z), f16(256e)) ~ 256*dot(z,e)
__global__ __launch_bounds__(256, 4) void mfma_dist_kernel(
    const _Float16* __restrict__ Ap, const _Float16* __restrict__ Bp,
    const float* __restrict__ esq, unsigned long long* __restrict__ cand) {
  __shared__ _Float16 As[128 * 64];  // [n][kk] 128B rows, g-groups XOR-swizzled
  __shared__ _Float16 Bs[128 * 64];  // [code][kk] same
  __shared__ unsigned long long mbuf[128][2];
  const int tid = threadIdx.x;
  const int lane = tid & 63;
  const int w = tid >> 6;
  const int wn = w & 1, wk = w >> 1;
  const int n0 = blockIdx.x * 128;
  const int quad = lane >> 4;
  const int l16 = lane & 15;

  float s1[4], s2[4];
  int i1[4], i2[4];
#pragma unroll
  for (int i = 0; i < 4; ++i) {
    s1[i] = 3.4e38f; s2[i] = 3.4e38f; i1[i] = 0; i2[i] = 0;
  }

  for (int kt = 0; kt < KT_ITERS; ++kt) {
    const int k0 = blockIdx.y * 1024 + kt * 128;
    f32x4 acc[4][4];
#pragma unroll
    for (int ci = 0; ci < 4; ++ci)
#pragma unroll
      for (int nj = 0; nj < 4; ++nj) acc[ci][nj] = (f32x4)0.f;

    for (int c = 0; c < 4; ++c) {
      // stage: lane-contiguous LDS writes; global g-group XOR'd by row&7
#pragma unroll
      for (int i = 0; i < 4; ++i) {
        const int off = i * 256 + tid;
        const int row = off >> 3;
        const int g = (off & 7) ^ (row & 7);
        const _Float16* gpA = Ap + (size_t)(n0 + row) * 256 + c * 64 + g * 8;
        const _Float16* gpB = Bp + (size_t)(k0 + row) * 256 + c * 64 + g * 8;
        _Float16* lpA = As + (size_t)(i * 256 + w * 64) * 8;
        _Float16* lpB = Bs + (size_t)(i * 256 + w * 64) * 8;
        __builtin_amdgcn_global_load_lds((gptr_t)gpA, (lptr_t)lpA, 16, 0, 0);
        __builtin_amdgcn_global_load_lds((gptr_t)gpB, (lptr_t)lpB, 16, 0, 0);
      }
      __syncthreads();
#pragma unroll
      for (int ks = 0; ks < 2; ++ks) {
        f16x8 a[4], b[4];
#pragma unroll
        for (int ci = 0; ci < 4; ++ci) {
          const int row = wk * 64 + ci * 16 + l16;
          const int g = (ks * 4 + quad) ^ (row & 7);
          a[ci] = *(const f16x8*)(Bs + row * 64 + g * 8);
        }
#pragma unroll
        for (int nj = 0; nj < 4; ++nj) {
          const int row = wn * 64 + nj * 16 + l16;
          const int g = (ks * 4 + quad) ^ (row & 7);
          b[nj] = *(const f16x8*)(As + row * 64 + g * 8);
        }
#pragma unroll
        for (int ci = 0; ci < 4; ++ci)
#pragma unroll
          for (int nj = 0; nj < 4; ++nj)
            acc[ci][nj] = __builtin_amdgcn_mfma_f32_16x16x32_f16(
                a[ci], b[nj], acc[ci][nj], 0, 0, 0);
      }
      __syncthreads();
    }
    // fold 128 codes into running top-2 (codes ascend -> ties keep low idx)
#pragma unroll
    for (int ci = 0; ci < 4; ++ci) {
      const int row0 = wk * 64 + ci * 16 + quad * 4;
      const float4 e4 = *(const float4*)&esq[k0 + row0];
      const float ev[4] = {e4.x, e4.y, e4.z, e4.w};
#pragma unroll
      for (int r = 0; r < 4; ++r) {
        const int code = k0 + row0 + r;
#pragma unroll
        for (int nj = 0; nj < 4; ++nj) {
          const float s = fmaf(acc[ci][nj][r], -0.0078125f, ev[r]);
          if (s < s1[nj]) {
            s2[nj] = s1[nj]; i2[nj] = i1[nj]; s1[nj] = s; i1[nj] = code;
          } else if (s < s2[nj]) {
            s2[nj] = s; i2[nj] = code;
          }
        }
      }
    }
  }
  // cross-lane merge over the 4 row-quads (lanes l, l^16, l^32, l^48)
  unsigned long long k1[4], k2[4];
#pragma unroll
  for (int nj = 0; nj < 4; ++nj) {
    float a1 = s1[nj], a2 = s2[nj];
    int ai1 = i1[nj], ai2 = i2[nj];
#pragma unroll
    for (int m = 16; m <= 32; m <<= 1) {
      float b1 = __shfl_xor(a1, m, 64);
      int bi1 = __shfl_xor(ai1, m, 64);
      float b2 = __shfl_xor(a2, m, 64);
      int bi2 = __shfl_xor(ai2, m, 64);
      if (b1 < a1 || (b1 == a1 && bi1 < ai1)) {
        float t = a1; a1 = b1; b1 = t;
        int ti = ai1; ai1 = bi1; bi1 = ti;
        t = a2; a2 = b2; b2 = t;
        ti = ai2; ai2 = bi2; bi2 = ti;
      }
      if (b1 < a2 || (b1 == a2 && bi1 < ai2)) { a2 = b1; ai2 = bi1; }
    }
    k1[nj] = pack_key(a1, ai1);
    k2[nj] = pack_key(a2, ai2);
  }
  // cross-wk merge inside the block: wk=1 posts its pairs, wk=0 finalizes
  if (wk == 1 && quad == 0) {
#pragma unroll
    for (int nj = 0; nj < 4; ++nj) {
      const int nl = wn * 64 + nj * 16 + l16;
      mbuf[nl][0] = k1[nj];
      mbuf[nl][1] = k2[nj];
    }
  }
  __syncthreads();
  if (wk == 0 && quad == 0) {
#pragma unroll
    for (int nj = 0; nj < 4; ++nj) {
      const int nl = wn * 64 + nj * 16 + l16;
      const unsigned long long b1 = mbuf[nl][0];
      const unsigned long long b2 = mbuf[nl][1];
      const unsigned long long m1 = min(k1[nj], b1);
      const unsigned long long m2 = min(max(k1[nj], b1), min(k2[nj], b2));
      const size_t n = n0 + nl;
      cand[(size_t)(blockIdx.y * 2 + 0) * N_VEC + n] = m1;
      cand[(size_t)(blockIdx.y * 2 + 1) * N_VEC + n] = m2;
    }
  }
}

// ---- merge 8 candidate slots; flag near-window positions -------------------
__global__ __launch_bounds__(256) void merge_kernel(
    const unsigned long long* __restrict__ cand, int* __restrict__ idx,
    int* __restrict__ list, unsigned int* __restrict__ count,
    unsigned long long* __restrict__ rfin) {
  const int n = blockIdx.x * 256 + threadIdx.x;
  unsigned long long m1 = ~0ull, m2 = ~0ull;
#pragma unroll
  for (int s = 0; s < NSLOT; ++s) {
    const unsigned long long c = cand[(size_t)s * N_VEC + n];
    if (c < m1) { m2 = m1; m1 = c; }
    else if (c < m2) { m2 = c; }
  }
  idx[n] = (int)(m1 & 0xFFFULL);
  const bool flag = key_score(m2) - key_score(m1) < WINDOW;
  rfin[n] = flag ? ~0ull : 0ull;
  if (flag) {
    const unsigned pos = atomicAdd(count, 1u);
    if (pos < N_VEC) list[pos] = n;
  }
}

// ---- rescan: work item = (position-pair, k-slice of 1024) ------------------
// frozen chain: d[k] = fl( fl(z_sq - fl(2*(float)dot64)) + e_sq[k] );
// winner via atomicMin on packed key (ties -> lowest k)
__global__ __launch_bounds__(256) void rescan_kernel(
    const float* __restrict__ z, const float* __restrict__ cb,
    const float* __restrict__ esq, const float* __restrict__ zsq,
    const int* __restrict__ list, const unsigned int* __restrict__ count,
    unsigned long long* __restrict__ rfin) {
  __shared__ float zrow[2][D];
  __shared__ int nloc[2];
  const int tid = threadIdx.x;
  const int lane = tid & 63;
  unsigned int cnt = *count;
  if (cnt > N_VEC) cnt = N_VEC;
  const unsigned nitems = ((cnt + 1) >> 1) * 4;
  for (unsigned item = blockIdx.x; item < nitems; item += gridDim.x) {
    const unsigned pair = item >> 2;
    const int slice = item & 3;
    __syncthreads();  // protect zrow/nloc reuse across grid-stride iters
    if (tid < 2) {
      const unsigned r = pair * 2 + tid;
      nloc[tid] = (r < cnt) ? list[r] : -1;
    }
    __syncthreads();
#pragma unroll
    for (int p = 0; p < 2; ++p) {
      const int n = nloc[p];
      if (n >= 0) {
        const int b = n >> 10, hw = n & 1023;
        zrow[p][tid] = z[((size_t)b << 18) + ((size_t)tid << 10) + hw];
      }
    }
    __syncthreads();
    const int n0 = nloc[0], n1 = nloc[1];
    const float zs0 = (n0 >= 0) ? zsq[n0] : 0.f;
    const float zs1 = (n1 >= 0) ? zsq[n1] : 0.f;
    unsigned long long best0 = ~0ull, best1 = ~0ull;
#pragma unroll
    for (int rr = 0; rr < 4; ++rr) {
      const int k = slice * 1024 + rr * 256 + tid;
      const float* row = cb + (size_t)k * D;
      double a0 = 0., a1 = 0., a2 = 0., a3 = 0.;
      double b0 = 0., b1 = 0., b2 = 0., b3 = 0.;
      for (int c = 0; c < D; c += 4) {
        const float4 r4 = *(const float4*)(row + c);
        const float4 z0 = *(const float4*)&zrow[0][c];
        const float4 z1 = *(const float4*)&zrow[1][c];
        a0 = fma((double)z0.x, (double)r4.x, a0);
        a1 = fma((double)z0.y, (double)r4.y, a1);
        a2 = fma((double)z0.z, (double)r4.z, a2);
        a3 = fma((double)z0.w, (double)r4.w, a3);
        b0 = fma((double)z1.x, (double)r4.x, b0);
        b1 = fma((double)z1.y, (double)r4.y, b1);
        b2 = fma((double)z1.z, (double)r4.z, b2);
        b3 = fma((double)z1.w, (double)r4.w, b3);
      }
      const float ek = esq[k];
      const float dot0 = (float)((a0 + a1) + (a2 + a3));
      const float d0 = __fadd_rn(__fsub_rn(zs0, __fmul_rn(2.0f, dot0)), ek);
      best0 = min(best0, pack_key(d0, k));
      const float dot1 = (float)((b0 + b1) + (b2 + b3));
      const float d1 = __fadd_rn(__fsub_rn(zs1, __fmul_rn(2.0f, dot1)), ek);
      best1 = min(best1, pack_key(d1, k));
    }
#pragma unroll
    for (int off = 32; off > 0; off >>= 1) {
      best0 = min(best0, __shfl_down(best0, off, 64));
      best1 = min(best1, __shfl_down(best1, off, 64));
    }
    if (lane == 0) {
      if (n0 >= 0) atomicMin(rfin + n0, best0);
      if (n1 >= 0) atomicMin(rfin + n1, best1);
    }
  }
}

// ---- gather z_q + indices + loss; fused rescan-resolve and finalize --------
__global__ __launch_bounds__(256) void gather_kernel(
    const float* __restrict__ z, const float* __restrict__ cb,
    const int* __restrict__ idxarr, const unsigned long long* __restrict__ rfin,
    float* __restrict__ out, float* __restrict__ loss_acc,
    unsigned int* __restrict__ done) {
  const int tid = threadIdx.x;
  const int n0 = blockIdx.x * 64;
  const int hwl = tid & 63;
  const int c0 = tid >> 6;
  const int n = n0 + hwl;
  const int b = n >> 10;
  const int hw = n & 1023;
  const unsigned long long rf = rfin[n];
  const int idx = rf ? (int)(rf & 0xFFFULL) : idxarr[n];
  if (tid < 64) out[(size_t)N_ELEM + 1 + n] = (float)idx;
  const float* crow = cb + (size_t)idx * D;
  const size_t obase = ((size_t)b << 18) + hw;
  float part = 0.f;
#pragma unroll
  for (int c = c0; c < D; c += 4) {
    const float v = crow[c];
    const size_t o = obase + ((size_t)c << 10);
    const float diff = v - z[o];
    out[o] = v;
    part = fmaf(diff, diff, part);
  }
#pragma unroll
  for (int off = 32; off > 0; off >>= 1) part += __shfl_down(part, off, 64);
  __shared__ float red[4];
  if ((tid & 63) == 0) red[tid >> 6] = part;
  __syncthreads();
  if (tid == 0) {
    atomicAdd(loss_acc, red[0] + red[1] + red[2] + red[3]);
    __threadfence();
    const unsigned old = atomicAdd(done, 1u);
    if (old == gridDim.x - 1) {
      const float total = atomicAdd(loss_acc, 0.0f);
      out[N_ELEM] = 1.25f * total * (1.0f / (float)N_ELEM);
    }
  }
}

extern "C" void kernel_launch(void* const* d_in, const int* in_sizes, int n_in,
                              void* d_out, int out_size, void* d_ws,
                              size_t ws_size, hipStream_t stream) {
  const float* z = (const float*)d_in[0];
  const float* cb = (const float*)d_in[1];
  float* out = (float*)d_out;
  char* ws = (char*)d_ws;
  float* loss_acc = (float*)(ws + WS_LOSS);
  unsigned int* count = (unsigned int*)(ws + WS_COUNT);
  unsigned int* done = (unsigned int*)(ws + WS_DONE);
  int* idx = (int*)(ws + WS_IDX);
  int* list = (int*)(ws + WS_LIST);
  float* esq = (float*)(ws + WS_ESQ);
  float* zsq = (float*)(ws + WS_ZSQ);
  unsigned long long* cand = (unsigned long long*)(ws + WS_CAND);
  _Float16* Ap = (_Float16*)(ws + WS_APACK);
  _Float16* Bp = (_Float16*)(ws + WS_BPACK);
  unsigned long long* rfin = (unsigned long long*)(ws + WS_RFIN);

  hipMemsetAsync(ws, 0, 256, stream);
  prep_kernel<<<PREP_BLOCKS, 256, 0, stream>>>(z, cb, esq, zsq, Ap, Bp);
  mfma_dist_kernel<<<dim3(N_VEC / 128, KSPLIT), 256, 0, stream>>>(Ap, Bp, esq,
                                                                  cand);
  merge_kernel<<<N_VEC / 256, 256, 0, stream>>>(cand, idx, list, count, rfin);
  rescan_kernel<<<2048, 256, 0, stream>>>(z, cb, esq, zsq, list, count, rfin);
  gather_kernel<<<N_VEC / 64, 256, 0, stream>>>(z, cb, idx, rfin, out,
                                                loss_acc, done);
}

// Round 9
// 343.809 us; speedup vs baseline: 2.5419x; 1.2385x over previous
//
#include <hip/hip_runtime.h>

#define K_CODES 4096
#define D 256
#define N_VEC 32768
#define N_ELEM 8388608   // 32*256*32*32
#define WINDOW 3.5e-4f
#define NSLOT 8
#define KSPLIT 4
#define KT_ITERS 8   // 1024 codes per block / 128
#define RG 8         // rescan positions per group
#define RSLICE 256   // rescan codes per slice

typedef _Float16 f16x8 __attribute__((ext_vector_type(8)));
typedef float f32x4 __attribute__((ext_vector_type(4)));
typedef const __attribute__((address_space(1))) _Float16* gptr_t;
typedef __attribute__((address_space(3))) _Float16* lptr_t;

// ws layout (bytes)
#define WS_LOSS 0
#define WS_COUNT 8
#define WS_DONE 16
#define WS_IDX 256
#define WS_LIST (WS_IDX + N_VEC * 4)
#define WS_ESQ (WS_LIST + N_VEC * 4)
#define WS_ZSQ (WS_ESQ + K_CODES * 4)
#define WS_CAND (WS_ZSQ + N_VEC * 4)
#define WS_APACK (WS_CAND + NSLOT * N_VEC * 8)          // f16[N_VEC][256]
#define WS_BPACK (WS_APACK + (size_t)N_VEC * 256 * 2)   // f16[K_CODES][256]
#define WS_RFIN (WS_BPACK + (size_t)K_CODES * 256 * 2)  // ull[N_VEC]

// prep fusion block regions
#define PREP_PZ 2048   // pack_z: 512 n-tiles x 4 c-tiles
#define PREP_PCB 256
#define PREP_ESQ 1024
#define PREP_ZSQ 128
#define PREP_BLOCKS (PREP_PZ + PREP_PCB + PREP_ESQ + PREP_ZSQ)

__device__ __forceinline__ unsigned long long pack_key(float s, int idx) {
  const unsigned u = __float_as_uint(s);
  const unsigned mk = (u & 0x80000000u) ? ~u : (u | 0x80000000u);
  return ((unsigned long long)mk << 12) | (unsigned long long)(unsigned)idx;
}
__device__ __forceinline__ float key_score(unsigned long long k) {
  const unsigned mk = (unsigned)(k >> 12);
  const unsigned u = (mk & 0x80000000u) ? (mk & 0x7fffffffu) : ~mk;
  return __uint_as_float(u);
}

// ---- e_sq body: fp32-squared terms, f64 accumulate, f32 round (frozen) -----
__device__ void esq_body(int bx, const float* __restrict__ cb,
                         float* __restrict__ esq) {
  const int lane = threadIdx.x & 63;
  const int k = bx * 4 + (threadIdx.x >> 6);
  const float* row = cb + (size_t)k * D;
  double s = 0.;
#pragma unroll
  for (int j = 0; j < 4; ++j) {
    const float v = row[lane + 64 * j];
    s += (double)__fmul_rn(v, v);
  }
#pragma unroll
  for (int off = 32; off > 0; off >>= 1) s += __shfl_down(s, off, 64);
  if (lane == 0) esq[k] = (float)s;
}

// ---- z_sq body (frozen: R3 — deterministic per-position order) -------------
__device__ void zsq_body(int bx, const float* __restrict__ z,
                         float* __restrict__ zsq) {
  const int n = bx * 256 + threadIdx.x;
  const int b = n >> 10;
  const int hw = n & 1023;
  const float* p = z + ((size_t)b << 18) + hw;
  double a0 = 0., a1 = 0., a2 = 0., a3 = 0.;
  for (int c = 0; c < D; c += 4) {
    const float v0 = p[(size_t)(c + 0) << 10];
    const float v1 = p[(size_t)(c + 1) << 10];
    const float v2 = p[(size_t)(c + 2) << 10];
    const float v3 = p[(size_t)(c + 3) << 10];
    a0 += (double)__fmul_rn(v0, v0);
    a1 += (double)__fmul_rn(v1, v1);
    a2 += (double)__fmul_rn(v2, v2);
    a3 += (double)__fmul_rn(v3, v3);
  }
  zsq[n] = (float)((a0 + a1) + (a2 + a3));
}

// ---- pack z -> Ap[n][256] f16(z) (single-f16) ------------------------------
__device__ void pack_z_body(int bx, int by, const float* __restrict__ z,
                            _Float16* __restrict__ Ap) {
  __shared__ float zs[64][65];
  const int t = threadIdx.x;
  const int n0 = bx * 64, c0 = by * 64;
  const int b = n0 >> 10, hw0 = n0 & 1023;
  const float* zb = z + ((size_t)b << 18) + hw0;
#pragma unroll
  for (int p = 0; p < 16; ++p) {
    const int cl = p * 4 + (t >> 6);
    zs[cl][t & 63] = zb[((size_t)(c0 + cl) << 10) + (t & 63)];
  }
  __syncthreads();
  const int nl = t >> 2, q = t & 3;
  f16x8 H0, H1;
#pragma unroll
  for (int j = 0; j < 8; ++j) {
    H0[j] = (_Float16)zs[q * 16 + j][nl];
    H1[j] = (_Float16)zs[q * 16 + 8 + j][nl];
  }
  _Float16* o = Ap + (size_t)(n0 + nl) * 256 + c0 + q * 16;
  *(f16x8*)o = H0;
  *((f16x8*)o + 1) = H1;
}

// ---- pack cb -> Bp[k][256] f16(256*e) --------------------------------------
__device__ void pack_cb_body(int bx, const float* __restrict__ cb,
                             _Float16* __restrict__ Bp) {
  const int tg = bx * 256 + threadIdx.x;  // 65536 total
  const int k = tg >> 4, q = tg & 15;
  const float* row = cb + (size_t)k * D + q * 16;
  f16x8 H0, H1;
#pragma unroll
  for (int j = 0; j < 8; ++j) {
    H0[j] = (_Float16)(row[j] * 256.f);
    H1[j] = (_Float16)(row[8 + j] * 256.f);
  }
  _Float16* o = Bp + (size_t)k * 256 + q * 16;
  *(f16x8*)o = H0;
  *((f16x8*)o + 1) = H1;
}

// ---- fused prep: one launch for esq + zsq + pack_z + pack_cb ---------------
__global__ __launch_bounds__(256) void prep_kernel(const float* __restrict__ z,
                                                   const float* __restrict__ cb,
                                                   float* __restrict__ esq,
                                                   float* __restrict__ zsq,
                                                   _Float16* __restrict__ Ap,
                                                   _Float16* __restrict__ Bp) {
  const int b = blockIdx.x;
  if (b < PREP_PZ) {
    pack_z_body(b & 511, b >> 9, z, Ap);
  } else if (b < PREP_PZ + PREP_PCB) {
    pack_cb_body(b - PREP_PZ, cb, Bp);
  } else if (b < PREP_PZ + PREP_PCB + PREP_ESQ) {
    esq_body(b - PREP_PZ - PREP_PCB, cb, esq);
  } else {
    zsq_body(b - PREP_PZ - PREP_PCB - PREP_ESQ, z, zsq);
  }
}

// ---- MFMA distance + top-2: 128n x 128codes tile, K=256, KSPLIT=4 ----------
// fine score = esq[k] - acc/128, acc = dot(f16(z), f16(256e)) ~ 256*dot(z,e)
__global__ __launch_bounds__(256, 4) void mfma_dist_kernel(
    const _Float16* __restrict__ Ap, const _Float16* __restrict__ Bp,
    const float* __restrict__ esq, unsigned long long* __restrict__ cand) {
  __shared__ _Float16 As[128 * 64];  // [n][kk] 128B rows, g-groups XOR-swizzled
  __shared__ _Float16 Bs[128 * 64];  // [code][kk] same
  __shared__ unsigned long long mbuf[128][2];
  const int tid = threadIdx.x;
  const int lane = tid & 63;
  const int w = tid >> 6;
  const int wn = w & 1, wk = w >> 1;
  const int n0 = blockIdx.x * 128;
  const int quad = lane >> 4;
  const int l16 = lane & 15;

  float s1[4], s2[4];
  int i1[4], i2[4];
#pragma unroll
  for (int i = 0; i < 4; ++i) {
    s1[i] = 3.4e38f; s2[i] = 3.4e38f; i1[i] = 0; i2[i] = 0;
  }

  for (int kt = 0; kt < KT_ITERS; ++kt) {
    const int k0 = blockIdx.y * 1024 + kt * 128;
    f32x4 acc[4][4];
#pragma unroll
    for (int ci = 0; ci < 4; ++ci)
#pragma unroll
      for (int nj = 0; nj < 4; ++nj) acc[ci][nj] = (f32x4)0.f;

    for (int c = 0; c < 4; ++c) {
      // stage: lane-contiguous LDS writes; global g-group XOR'd by row&7
#pragma unroll
      for (int i = 0; i < 4; ++i) {
        const int off = i * 256 + tid;
        const int row = off >> 3;
        const int g = (off & 7) ^ (row & 7);
        const _Float16* gpA = Ap + (size_t)(n0 + row) * 256 + c * 64 + g * 8;
        const _Float16* gpB = Bp + (size_t)(k0 + row) * 256 + c * 64 + g * 8;
        _Float16* lpA = As + (size_t)(i * 256 + w * 64) * 8;
        _Float16* lpB = Bs + (size_t)(i * 256 + w * 64) * 8;
        __builtin_amdgcn_global_load_lds((gptr_t)gpA, (lptr_t)lpA, 16, 0, 0);
        __builtin_amdgcn_global_load_lds((gptr_t)gpB, (lptr_t)lpB, 16, 0, 0);
      }
      __syncthreads();
#pragma unroll
      for (int ks = 0; ks < 2; ++ks) {
        f16x8 a[4], b[4];
#pragma unroll
        for (int ci = 0; ci < 4; ++ci) {
          const int row = wk * 64 + ci * 16 + l16;
          const int g = (ks * 4 + quad) ^ (row & 7);
          a[ci] = *(const f16x8*)(Bs + row * 64 + g * 8);
        }
#pragma unroll
        for (int nj = 0; nj < 4; ++nj) {
          const int row = wn * 64 + nj * 16 + l16;
          const int g = (ks * 4 + quad) ^ (row & 7);
          b[nj] = *(const f16x8*)(As + row * 64 + g * 8);
        }
#pragma unroll
        for (int ci = 0; ci < 4; ++ci)
#pragma unroll
          for (int nj = 0; nj < 4; ++nj)
            acc[ci][nj] = __builtin_amdgcn_mfma_f32_16x16x32_f16(
                a[ci], b[nj], acc[ci][nj], 0, 0, 0);
      }
      __syncthreads();
    }
    // fold 128 codes into running top-2 (codes ascend -> ties keep low idx)
#pragma unroll
    for (int ci = 0; ci < 4; ++ci) {
      const int row0 = wk * 64 + ci * 16 + quad * 4;
      const float4 e4 = *(const float4*)&esq[k0 + row0];
      const float ev[4] = {e4.x, e4.y, e4.z, e4.w};
#pragma unroll
      for (int r = 0; r < 4; ++r) {
        const int code = k0 + row0 + r;
#pragma unroll
        for (int nj = 0; nj < 4; ++nj) {
          const float s = fmaf(acc[ci][nj][r], -0.0078125f, ev[r]);
          if (s < s1[nj]) {
            s2[nj] = s1[nj]; i2[nj] = i1[nj]; s1[nj] = s; i1[nj] = code;
          } else if (s < s2[nj]) {
            s2[nj] = s; i2[nj] = code;
          }
        }
      }
    }
  }
  // cross-lane merge over the 4 row-quads (lanes l, l^16, l^32, l^48)
  unsigned long long k1[4], k2[4];
#pragma unroll
  for (int nj = 0; nj < 4; ++nj) {
    float a1 = s1[nj], a2 = s2[nj];
    int ai1 = i1[nj], ai2 = i2[nj];
#pragma unroll
    for (int m = 16; m <= 32; m <<= 1) {
      float b1 = __shfl_xor(a1, m, 64);
      int bi1 = __shfl_xor(ai1, m, 64);
      float b2 = __shfl_xor(a2, m, 64);
      int bi2 = __shfl_xor(ai2, m, 64);
      if (b1 < a1 || (b1 == a1 && bi1 < ai1)) {
        float t = a1; a1 = b1; b1 = t;
        int ti = ai1; ai1 = bi1; bi1 = ti;
        t = a2; a2 = b2; b2 = t;
        ti = ai2; ai2 = bi2; bi2 = ti;
      }
      if (b1 < a2 || (b1 == a2 && bi1 < ai2)) { a2 = b1; ai2 = bi1; }
    }
    k1[nj] = pack_key(a1, ai1);
    k2[nj] = pack_key(a2, ai2);
  }
  // cross-wk merge inside the block: wk=1 posts its pairs, wk=0 finalizes
  if (wk == 1 && quad == 0) {
#pragma unroll
    for (int nj = 0; nj < 4; ++nj) {
      const int nl = wn * 64 + nj * 16 + l16;
      mbuf[nl][0] = k1[nj];
      mbuf[nl][1] = k2[nj];
    }
  }
  __syncthreads();
  if (wk == 0 && quad == 0) {
#pragma unroll
    for (int nj = 0; nj < 4; ++nj) {
      const int nl = wn * 64 + nj * 16 + l16;
      const unsigned long long b1 = mbuf[nl][0];
      const unsigned long long b2 = mbuf[nl][1];
      const unsigned long long m1 = min(k1[nj], b1);
      const unsigned long long m2 = min(max(k1[nj], b1), min(k2[nj], b2));
      const size_t n = n0 + nl;
      cand[(size_t)(blockIdx.y * 2 + 0) * N_VEC + n] = m1;
      cand[(size_t)(blockIdx.y * 2 + 1) * N_VEC + n] = m2;
    }
  }
}

// ---- merge 8 candidate slots; flag near-window positions -------------------
__global__ __launch_bounds__(256) void merge_kernel(
    const unsigned long long* __restrict__ cand, int* __restrict__ idx,
    int* __restrict__ list, unsigned int* __restrict__ count,
    unsigned long long* __restrict__ rfin) {
  const int n = blockIdx.x * 256 + threadIdx.x;
  unsigned long long m1 = ~0ull, m2 = ~0ull;
#pragma unroll
  for (int s = 0; s < NSLOT; ++s) {
    const unsigned long long c = cand[(size_t)s * N_VEC + n];
    if (c < m1) { m2 = m1; m1 = c; }
    else if (c < m2) { m2 = c; }
  }
  idx[n] = (int)(m1 & 0xFFFULL);
  const bool flag = key_score(m2) - key_score(m1) < WINDOW;
  rfin[n] = flag ? ~0ull : 0ull;
  if (flag) {
    const unsigned pos = atomicAdd(count, 1u);
    if (pos < N_VEC) list[pos] = n;
  }
}

// ---- rescan v3: item = (8-position group, 256-code slice) ------------------
// frozen chain: d[k] = fl( fl(z_sq - fl(2*(float)dot64)) + e_sq[k] );
// winner via atomicMin on packed key (ties -> lowest k)
__global__ __launch_bounds__(256) void rescan_kernel(
    const float* __restrict__ z, const float* __restrict__ cb,
    const float* __restrict__ esq, const float* __restrict__ zsq,
    const int* __restrict__ list, const unsigned int* __restrict__ count,
    unsigned long long* __restrict__ rfin) {
  __shared__ double zrow[RG][D];  // 16 KB, pre-converted f64; reads broadcast
  __shared__ int nloc[RG];
  __shared__ float zsv[RG];
  const int tid = threadIdx.x;
  const int lane = tid & 63;
  unsigned int cnt = *count;
  if (cnt > N_VEC) cnt = N_VEC;
  const unsigned G = (cnt + RG - 1) / RG;
  const unsigned nitems = G * (K_CODES / RSLICE);
  for (unsigned item = blockIdx.x; item < nitems; item += gridDim.x) {
    const unsigned g = item >> 4;
    const int s = item & 15;
    __syncthreads();  // protect zrow/nloc reuse across grid-stride iters
    if (tid < RG) {
      const unsigned r = g * RG + tid;
      const int n = (r < cnt) ? list[r] : list[cnt - 1];  // dup-pad: idempotent
      nloc[tid] = n;
      zsv[tid] = zsq[n];
    }
    __syncthreads();
    for (int i = tid; i < RG * D; i += 256) {
      const int p = i >> 8, c = i & 255;
      const int n = nloc[p];
      const int b = n >> 10, hw = n & 1023;
      zrow[p][c] = (double)z[((size_t)b << 18) + ((size_t)c << 10) + hw];
    }
    __syncthreads();
    const int k = s * RSLICE + tid;
    const float* row = cb + (size_t)k * D;
    double acc[RG];
#pragma unroll
    for (int p = 0; p < RG; ++p) acc[p] = 0.;
    for (int c = 0; c < D; c += 4) {
      const float4 r4 = *(const float4*)(row + c);
      const double rx = (double)r4.x, ry = (double)r4.y;
      const double rz = (double)r4.z, rw = (double)r4.w;
#pragma unroll
      for (int p = 0; p < RG; ++p) {
        const double2 za = *(const double2*)&zrow[p][c];
        const double2 zb = *(const double2*)&zrow[p][c + 2];
        double a = acc[p];
        a = fma(za.x, rx, a);
        a = fma(za.y, ry, a);
        a = fma(zb.x, rz, a);
        a = fma(zb.y, rw, a);
        acc[p] = a;
      }
    }
    const float ek = esq[k];
    unsigned long long best[RG];
#pragma unroll
    for (int p = 0; p < RG; ++p) {
      const float dotf = (float)acc[p];
      const float d = __fadd_rn(__fsub_rn(zsv[p], __fmul_rn(2.0f, dotf)), ek);
      best[p] = pack_key(d, k);
    }
#pragma unroll
    for (int p = 0; p < RG; ++p) {
#pragma unroll
      for (int off = 32; off > 0; off >>= 1)
        best[p] = min(best[p], __shfl_down(best[p], off, 64));
    }
    if (lane == 0) {
#pragma unroll
      for (int p = 0; p < RG; ++p) atomicMin(rfin + nloc[p], best[p]);
    }
  }
}

// ---- gather z_q + indices + loss; fused rescan-resolve and finalize --------
__global__ __launch_bounds__(256) void gather_kernel(
    const float* __restrict__ z, const float* __restrict__ cb,
    const int* __restrict__ idxarr, const unsigned long long* __restrict__ rfin,
    float* __restrict__ out, float* __restrict__ loss_acc,
    unsigned int* __restrict__ done) {
  const int tid = threadIdx.x;
  const int n0 = blockIdx.x * 64;
  const int hwl = tid & 63;
  const int c0 = tid >> 6;
  const int n = n0 + hwl;
  const int b = n >> 10;
  const int hw = n & 1023;
  const unsigned long long rf = rfin[n];
  const int idx = rf ? (int)(rf & 0xFFFULL) : idxarr[n];
  if (tid < 64) out[(size_t)N_ELEM + 1 + n] = (float)idx;
  const float* crow = cb + (size_t)idx * D;
  const size_t obase = ((size_t)b << 18) + hw;
  float part = 0.f;
#pragma unroll
  for (int c = c0; c < D; c += 4) {
    const float v = crow[c];
    const size_t o = obase + ((size_t)c << 10);
    const float diff = v - z[o];
    out[o] = v;
    part = fmaf(diff, diff, part);
  }
#pragma unroll
  for (int off = 32; off > 0; off >>= 1) part += __shfl_down(part, off, 64);
  __shared__ float red[4];
  if ((tid & 63) == 0) red[tid >> 6] = part;
  __syncthreads();
  if (tid == 0) {
    atomicAdd(loss_acc, red[0] + red[1] + red[2] + red[3]);
    __threadfence();
    const unsigned old = atomicAdd(done, 1u);
    if (old == gridDim.x - 1) {
      const float total = atomicAdd(loss_acc, 0.0f);
      out[N_ELEM] = 1.25f * total * (1.0f / (float)N_ELEM);
    }
  }
}

extern "C" void kernel_launch(void* const* d_in, const int* in_sizes, int n_in,
                              void* d_out, int out_size, void* d_ws,
                              size_t ws_size, hipStream_t stream) {
  const float* z = (const float*)d_in[0];
  const float* cb = (const float*)d_in[1];
  float* out = (float*)d_out;
  char* ws = (char*)d_ws;
  float* loss_acc = (float*)(ws + WS_LOSS);
  unsigned int* count = (unsigned int*)(ws + WS_COUNT);
  unsigned int* done = (unsigned int*)(ws + WS_DONE);
  int* idx = (int*)(ws + WS_IDX);
  int* list = (int*)(ws + WS_LIST);
  float* esq = (float*)(ws + WS_ESQ);
  float* zsq = (float*)(ws + WS_ZSQ);
  unsigned long long* cand = (unsigned long long*)(ws + WS_CAND);
  _Float16* Ap = (_Float16*)(ws + WS_APACK);
  _Float16* Bp = (_Float16*)(ws + WS_BPACK);
  unsigned long long* rfin = (unsigned long long*)(ws + WS_RFIN);

  hipMemsetAsync(ws, 0, 256, stream);
  prep_kernel<<<PREP_BLOCKS, 256, 0, stream>>>(z, cb, esq, zsq, Ap, Bp);
  mfma_dist_kernel<<<dim3(N_VEC / 128, KSPLIT), 256, 0, stream>>>(Ap, Bp, esq,
                                                                  cand);
  merge_kernel<<<N_VEC / 256, 256, 0, stream>>>(cand, idx, list, count, rfin);
  rescan_kernel<<<2048, 256, 0, stream>>>(z, cb, esq, zsq, list, count, rfin);
  gather_kernel<<<N_VEC / 64, 256, 0, stream>>>(z, cb, idx, rfin, out,
                                                loss_acc, done);
}